// Round 2
// baseline (399.454 us; speedup 1.0000x reference)
//
#include <hip/hip_runtime.h>
#include <hip/hip_bf16.h>

// Performer (FAVOR+) attention, bf16-MFMA fused two-pass. b=4 h=8 L=8192 d=64 m=256.
// R1 (occupancy+pipeline): grid 512->1024, XCD-aware bh grouping, register
// prefetch of K/V/Q tiles, kernel-B operand-swapped proj (b64 Q' stores),
// kv^T fragments in registers, kvT/Qp LDS union (56.5->39.7 KB -> 4 blk/CU).
// R2: resubmit of R1 (round lost to container infra failure; kernel re-audited:
// alignment, races, bounds all clean).

#define BH 32
#define LL 8192
#define DD 64
#define MM 256
#define NRM 0.35355339059327373f   // 64^-0.25
#define SQS 0.0625f                // 0.5*NRM^2
#define EPSK 1e-6f
#define EPSZ 1e-6f
#define NTILE 8                    // 32-row tiles per block
#define RPB 256                    // rows per block

typedef __attribute__((ext_vector_type(8))) short bf16x8;
typedef __attribute__((ext_vector_type(4))) float f32x4;
#define MFMA(a, b, c) __builtin_amdgcn_mfma_f32_16x16x32_bf16(a, b, c, 0, 0, 0)

static __device__ __forceinline__ short f2bf(float x) {
    union { float f; unsigned u; } c{x};
    unsigned r = c.u + 0x7fffu + ((c.u >> 16) & 1u);   // RNE
    return (short)(r >> 16);
}

// 1024 blocks; hw round-robins blockIdx%8 over XCDs -> same-bh blocks share an XCD/L2.
static __device__ __forceinline__ void decode_block(int i, int& bh, int& chunk) {
    bh = ((i & 7) << 2) | ((i >> 3) & 3);
    chunk = i >> 5;
}

// Load P fragments (NRM folded): element jj = P[64*wv + mt*16 + l16][ks*32 + quad*8 + jj]*NRM
static __device__ __forceinline__ void load_pfrags(
    const float* __restrict__ Pm, int wv, int quad, int l16, bf16x8 pb[2][4])
{
#pragma unroll
    for (int ks = 0; ks < 2; ++ks)
#pragma unroll
        for (int mt = 0; mt < 4; ++mt) {
            const float* pr = Pm + (wv * 64 + mt * 16 + l16) * DD + ks * 32 + quad * 8;
            float4 p0 = *(const float4*)pr;
            float4 p1 = *(const float4*)(pr + 4);
            bf16x8 f;
            f[0] = f2bf(p0.x * NRM); f[1] = f2bf(p0.y * NRM);
            f[2] = f2bf(p0.z * NRM); f[3] = f2bf(p0.w * NRM);
            f[4] = f2bf(p1.x * NRM); f[5] = f2bf(p1.y * NRM);
            f[6] = f2bf(p1.z * NRM); f[7] = f2bf(p1.w * NRM);
            pb[ks][mt] = f;
        }
}

// ---------------- Kernel A: kv += K'^T V, ksum += colsum(K') ----------------
__global__ __launch_bounds__(256, 3) void kv_kernel(
    const float* __restrict__ kin, const float* __restrict__ vin,
    const float* __restrict__ Pm, float* __restrict__ kv, float* __restrict__ ksum)
{
    __shared__ short Kb[32 * 72];    // K tile bf16 [l][d], stride 72
    __shared__ short Vt[64 * 40];    // V^T tile   [d][l], stride 40
    __shared__ short Ktp[256 * 40];  // K'^T tile  [m][l], stride 40
    __shared__ float cl_lds[32];     // eps - 0.5*NRM^2*|k|^2 per row

    const int t = threadIdx.x;
    const int lane = t & 63, wv = t >> 6;
    const int quad = lane >> 4, l16 = lane & 15;
    int bh, chunk;
    decode_block(blockIdx.x, bh, chunk);

    bf16x8 pb[2][4];
    load_pfrags(Pm, wv, quad, l16, pb);

    f32x4 kvacc[4][4];
#pragma unroll
    for (int mt = 0; mt < 4; ++mt)
#pragma unroll
        for (int dt = 0; dt < 4; ++dt) kvacc[mt][dt] = (f32x4)0.f;
    float ksacc[4] = {0.f, 0.f, 0.f, 0.f};

    const size_t base = ((size_t)bh * LL + (size_t)chunk * RPB) * DD;
    const float* kb = kin + base;
    const float* vb = vin + base;
    const int sl = t >> 4, sd4 = t & 15;

    // register double-buffer: prologue load of tile 0
    float4 kreg[2], vreg[2];
#pragma unroll
    for (int half = 0; half < 2; ++half) {
        const int gi = (sl + half * 16) * DD + sd4 * 4;
        kreg[half] = *(const float4*)(kb + gi);
        vreg[half] = *(const float4*)(vb + gi);
    }

    for (int tile = 0; tile < NTILE; ++tile) {
        __syncthreads();
        // --- stage prefetched regs -> LDS (bf16), row norms ---
#pragma unroll
        for (int half = 0; half < 2; ++half) {
            const int l = sl + half * 16;
            const float4 kf = kreg[half];
            const float4 vf = vreg[half];
            float sq = kf.x * kf.x + kf.y * kf.y + kf.z * kf.z + kf.w * kf.w;
            sq += __shfl_xor(sq, 1); sq += __shfl_xor(sq, 2);
            sq += __shfl_xor(sq, 4); sq += __shfl_xor(sq, 8);
            if (sd4 == 0) cl_lds[l] = EPSK - SQS * sq;
            union { short s[4]; unsigned long long u; } uk;
            uk.s[0] = f2bf(kf.x); uk.s[1] = f2bf(kf.y);
            uk.s[2] = f2bf(kf.z); uk.s[3] = f2bf(kf.w);
            *(unsigned long long*)&Kb[l * 72 + sd4 * 4] = uk.u;
            Vt[(sd4 * 4 + 0) * 40 + l] = f2bf(vf.x);
            Vt[(sd4 * 4 + 1) * 40 + l] = f2bf(vf.y);
            Vt[(sd4 * 4 + 2) * 40 + l] = f2bf(vf.z);
            Vt[(sd4 * 4 + 3) * 40 + l] = f2bf(vf.w);
        }
        // --- issue next tile's global loads; latency hides under MFMA/exp ---
        if (tile + 1 < NTILE) {
#pragma unroll
            for (int half = 0; half < 2; ++half) {
                const int gi = ((tile + 1) * 32 + sl + half * 16) * DD + sd4 * 4;
                kreg[half] = *(const float4*)(kb + gi);
                vreg[half] = *(const float4*)(vb + gi);
            }
        }
        __syncthreads();
        // --- proj MFMA + exp, lt-outer (pt live range 16 VGPRs) ---
#pragma unroll
        for (int lt = 0; lt < 2; ++lt) {
            f32x4 ptl[4];
#pragma unroll
            for (int mt = 0; mt < 4; ++mt) ptl[mt] = (f32x4)0.f;
#pragma unroll
            for (int ks = 0; ks < 2; ++ks) {
                const bf16x8 af = *(const bf16x8*)&Kb[(lt * 16 + l16) * 72 + ks * 32 + quad * 8];
#pragma unroll
                for (int mt = 0; mt < 4; ++mt)
                    ptl[mt] = MFMA(af, pb[ks][mt], ptl[mt]);
            }
#pragma unroll
            for (int mt = 0; mt < 4; ++mt) {
                union { short s[4]; unsigned long long u; } uo;
#pragma unroll
                for (int r = 0; r < 4; ++r) {
                    const float w = __expf(ptl[mt][r] + cl_lds[lt * 16 + quad * 4 + r]);
                    ksacc[mt] += w;
                    uo.s[r] = f2bf(w);
                }
                *(unsigned long long*)&Ktp[(wv * 64 + mt * 16 + l16) * 40 + lt * 16 + quad * 4] = uo.u;
            }
        }
        // --- kv MFMA: kv[m][d] += sum_l K'^T[m][l] V[l][d] ---
        bf16x8 aK[4], bV[4];
#pragma unroll
        for (int mt = 0; mt < 4; ++mt)
            aK[mt] = *(const bf16x8*)&Ktp[(wv * 64 + mt * 16 + l16) * 40 + quad * 8];
#pragma unroll
        for (int dt = 0; dt < 4; ++dt)
            bV[dt] = *(const bf16x8*)&Vt[(dt * 16 + l16) * 40 + quad * 8];
#pragma unroll
        for (int mt = 0; mt < 4; ++mt)
#pragma unroll
            for (int dt = 0; dt < 4; ++dt)
                kvacc[mt][dt] = MFMA(aK[mt], bV[dt], kvacc[mt][dt]);
    }
    // --- epilogue: atomics into workspace ---
    float* kvg = kv + (size_t)bh * MM * DD;
#pragma unroll
    for (int mt = 0; mt < 4; ++mt) {
        float r = ksacc[mt];
        r += __shfl_xor(r, 16); r += __shfl_xor(r, 32);
        if (quad == 0) atomicAdd(ksum + bh * MM + wv * 64 + mt * 16 + l16, r);
#pragma unroll
        for (int dt = 0; dt < 4; ++dt)
#pragma unroll
            for (int rg = 0; rg < 4; ++rg)
                atomicAdd(kvg + (wv * 64 + mt * 16 + quad * 4 + rg) * DD + dt * 16 + l16,
                          kvacc[mt][dt][rg]);
    }
}

// ---------------- Kernel B: out = (Q' kv) * z ------------------------------
__global__ __launch_bounds__(256, 4) void out_kernel(
    const float* __restrict__ qin, const float* __restrict__ Pm,
    const float* __restrict__ kv, const float* __restrict__ ksum,
    float* __restrict__ out)
{
    __shared__ short sm[64 * 264];    // kv^T staging [d][m], then Q' tile [32][264]
    __shared__ short Qb[32 * 72];     // Q tile bf16 [l][d]
    __shared__ float ks_lds[MM];
    __shared__ float cl_lds[32];
    __shared__ float z_lds[32];

    const int t = threadIdx.x;
    const int lane = t & 63, wv = t >> 6;
    const int quad = lane >> 4, l16 = lane & 15;
    int bh, chunk;
    decode_block(blockIdx.x, bh, chunk);

    bf16x8 pb[2][4];
    load_pfrags(Pm, wv, quad, l16, pb);

    // --- stage kv^T (bf16 transposed) + ksum, once per block ---
    const float* kvg = kv + (size_t)bh * MM * DD;
#pragma unroll
    for (int it = 0; it < 16; ++it) {
        const int i = t + it * 256;          // float4 index over [256][16]
        const int m = i >> 4, d4 = i & 15;
        const float4 f = *(const float4*)(kvg + m * DD + d4 * 4);
        sm[(d4 * 4 + 0) * 264 + m] = f2bf(f.x);
        sm[(d4 * 4 + 1) * 264 + m] = f2bf(f.y);
        sm[(d4 * 4 + 2) * 264 + m] = f2bf(f.z);
        sm[(d4 * 4 + 3) * 264 + m] = f2bf(f.w);
    }
    ks_lds[t] = ksum[bh * MM + t];
    __syncthreads();

    // --- hoist kv^T fragments to registers (one-time; frees sm for Q') ---
    bf16x8 bk[8];
#pragma unroll
    for (int ks = 0; ks < 8; ++ks)
        bk[ks] = *(const bf16x8*)&sm[(wv * 16 + l16) * 264 + ks * 32 + quad * 8];

    const size_t base = ((size_t)bh * LL + (size_t)chunk * RPB) * DD;
    const float* qb = qin + base;
    float* ob = out + base;
    const int sl = t >> 4, sd4 = t & 15;

    float4 qreg[2];
#pragma unroll
    for (int half = 0; half < 2; ++half)
        qreg[half] = *(const float4*)(qb + (sl + half * 16) * DD + sd4 * 4);

    for (int tile = 0; tile < NTILE; ++tile) {
        __syncthreads();   // bk extraction / prev-tile sm+z reads complete
        if (t < 32) z_lds[t] = 0.f;
#pragma unroll
        for (int half = 0; half < 2; ++half) {
            const int l = sl + half * 16;
            const float4 qf = qreg[half];
            float sq = qf.x * qf.x + qf.y * qf.y + qf.z * qf.z + qf.w * qf.w;
            sq += __shfl_xor(sq, 1); sq += __shfl_xor(sq, 2);
            sq += __shfl_xor(sq, 4); sq += __shfl_xor(sq, 8);
            if (sd4 == 0) cl_lds[l] = EPSK - SQS * sq;
            union { short s[4]; unsigned long long u; } uq;
            uq.s[0] = f2bf(qf.x); uq.s[1] = f2bf(qf.y);
            uq.s[2] = f2bf(qf.z); uq.s[3] = f2bf(qf.w);
            *(unsigned long long*)&Qb[l * 72 + sd4 * 4] = uq.u;
        }
        if (tile + 1 < NTILE) {
#pragma unroll
            for (int half = 0; half < 2; ++half)
                qreg[half] = *(const float4*)(qb + ((tile + 1) * 32 + sl + half * 16) * DD + sd4 * 4);
        }
        __syncthreads();

        // --- proj MFMA, SWAPPED operands: A=P-frags, B=Q-frags -> P'[m][l].
        // Lane (quad,l16) reg r holds proj[m=wv*64+mt*16+quad*4+r][l=lt*16+l16],
        // so exp-output is m-contiguous per lane -> b64 Q'[l][m] stores.
        bf16x8 qf2[2][2];
#pragma unroll
        for (int ks2 = 0; ks2 < 2; ++ks2)
#pragma unroll
            for (int lt = 0; lt < 2; ++lt)
                qf2[ks2][lt] = *(const bf16x8*)&Qb[(lt * 16 + l16) * 72 + ks2 * 32 + quad * 8];
        const float clv0 = cl_lds[l16];
        const float clv1 = cl_lds[16 + l16];
        float zp0 = 0.f, zp1 = 0.f;
#pragma unroll
        for (int mt = 0; mt < 4; ++mt) {
            f32x4 pt0 = (f32x4)0.f, pt1 = (f32x4)0.f;
#pragma unroll
            for (int ks2 = 0; ks2 < 2; ++ks2) {
                pt0 = MFMA(pb[ks2][mt], qf2[ks2][0], pt0);
                pt1 = MFMA(pb[ks2][mt], qf2[ks2][1], pt1);
            }
            const float4 km4 = *(const float4*)&ks_lds[wv * 64 + mt * 16 + quad * 4];
            const float km[4] = {km4.x, km4.y, km4.z, km4.w};
            union { short s[4]; unsigned long long u; } u0, u1;
#pragma unroll
            for (int r = 0; r < 4; ++r) {
                const float w0 = __expf(pt0[r] + clv0);
                const float w1 = __expf(pt1[r] + clv1);
                zp0 += w0 * km[r];
                zp1 += w1 * km[r];
                u0.s[r] = f2bf(w0);
                u1.s[r] = f2bf(w1);
            }
            *(unsigned long long*)&sm[(l16) * 264 + wv * 64 + mt * 16 + quad * 4] = u0.u;
            *(unsigned long long*)&sm[(16 + l16) * 264 + wv * 64 + mt * 16 + quad * 4] = u1.u;
        }
        // z: lane covers 16 m-values; reduce over quad, then cross-wave atomic
        zp0 += __shfl_xor(zp0, 16); zp0 += __shfl_xor(zp0, 32);
        zp1 += __shfl_xor(zp1, 16); zp1 += __shfl_xor(zp1, 32);
        if (lane < 16) {
            atomicAdd(&z_lds[l16], zp0);
            atomicAdd(&z_lds[16 + l16], zp1);
        }
        __syncthreads();

        // --- out MFMA: out[l][d] = sum_m Q'[l][m] kv[m][d]; kv frags in regs ---
        f32x4 oc0 = (f32x4)0.f, oc1 = (f32x4)0.f;
#pragma unroll
        for (int ks = 0; ks < 8; ++ks) {
            const bf16x8 aq0 = *(const bf16x8*)&sm[(l16) * 264 + ks * 32 + quad * 8];
            const bf16x8 aq1 = *(const bf16x8*)&sm[(16 + l16) * 264 + ks * 32 + quad * 8];
            oc0 = MFMA(aq0, bk[ks], oc0);
            oc1 = MFMA(aq1, bk[ks], oc1);
        }
#pragma unroll
        for (int r = 0; r < 4; ++r) {
            const int row0 = quad * 4 + r;
            const float z0 = 1.f / (z_lds[row0] + EPSZ);
            ob[(size_t)(tile * 32 + row0) * DD + wv * 16 + l16] = oc0[r] * z0;
            const int row1 = 16 + quad * 4 + r;
            const float z1 = 1.f / (z_lds[row1] + EPSZ);
            ob[(size_t)(tile * 32 + row1) * DD + wv * 16 + l16] = oc1[r] * z1;
        }
    }
}

extern "C" void kernel_launch(void* const* d_in, const int* in_sizes, int n_in,
                              void* d_out, int out_size, void* d_ws, size_t ws_size,
                              hipStream_t stream) {
    const float* q  = (const float*)d_in[0];
    const float* k  = (const float*)d_in[1];
    const float* v  = (const float*)d_in[2];
    const float* Pm = (const float*)d_in[3];

    float* kvw = (float*)d_ws;                       // [BH, M, D]
    float* ksw = kvw + (size_t)BH * MM * DD;         // [BH, M]

    hipMemsetAsync(d_ws, 0, ((size_t)BH * MM * DD + (size_t)BH * MM) * sizeof(float), stream);
    hipLaunchKernelGGL(kv_kernel, dim3(1024), dim3(256), 0, stream, k, v, Pm, kvw, ksw);
    hipLaunchKernelGGL(out_kernel, dim3(1024), dim3(256), 0, stream, q, Pm, kvw, ksw, (float*)d_out);
}

// Round 6
// 327.007 us; speedup vs baseline: 1.2215x; 1.2215x over previous
//
#include <hip/hip_runtime.h>
#include <hip/hip_bf16.h>

// Performer (FAVOR+) attention, bf16-MFMA fused two-pass. b=4 h=8 L=8192 d=64 m=256.
// R6: resubmit of R5 (round lost to container infra failure, second time).
// Composition of harness-verified parts:
//  - kv_kernel: exact R0 body, grid 512 (verified 101.8us; R2 showed 1024 blocks
//    => atomic WRITE_SIZE 33->110MB => 192us regression).
//  - out_kernel: exact R2 body, grid 1024 (verified pass; swapped-proj b64 Q'
//    stores, kvT/Q' LDS union, kv-frags-in-regs; no global atomics so extra
//    blocks raise occupancy safely).
// Cooperative fusion abandoned (R3/R4: identical absmax across different
// memory-ordering variants == all-zero output == coop launch silently dropped
// under harness graph capture).

#define BH 32
#define LL 8192
#define DD 64
#define MM 256
#define NRM 0.35355339059327373f   // 64^-0.25
#define SQS 0.0625f                // 0.5*NRM^2
#define EPSK 1e-6f
#define EPSZ 1e-6f
#define NTILE 8                    // out_kernel: 32-row tiles per block
#define RPB 256                    // out_kernel: rows per block

typedef __attribute__((ext_vector_type(8))) short bf16x8;
typedef __attribute__((ext_vector_type(4))) float f32x4;
#define MFMA(a, b, c) __builtin_amdgcn_mfma_f32_16x16x32_bf16(a, b, c, 0, 0, 0)

static __device__ __forceinline__ short f2bf(float x) {
    union { float f; unsigned u; } c{x};
    unsigned r = c.u + 0x7fffu + ((c.u >> 16) & 1u);   // RNE
    return (short)(r >> 16);
}

// out_kernel 1024-block mapping; hw round-robins blockIdx%8 over XCDs ->
// same-bh blocks share an XCD/L2 for the kv staging reads.
static __device__ __forceinline__ void decode_block(int i, int& bh, int& chunk) {
    bh = ((i & 7) << 2) | ((i >> 3) & 3);
    chunk = i >> 5;
}

// P fragments (NRM folded): elem jj = P[64*wv + mt*16 + l16][ks*32 + quad*8 + jj]*NRM
static __device__ __forceinline__ void load_pfrags(
    const float* __restrict__ Pm, int wv, int quad, int l16, bf16x8 pb[2][4])
{
#pragma unroll
    for (int ks = 0; ks < 2; ++ks)
#pragma unroll
        for (int mt = 0; mt < 4; ++mt) {
            const float* pr = Pm + (wv * 64 + mt * 16 + l16) * DD + ks * 32 + quad * 8;
            float4 p0 = *(const float4*)pr;
            float4 p1 = *(const float4*)(pr + 4);
            bf16x8 f;
            f[0] = f2bf(p0.x * NRM); f[1] = f2bf(p0.y * NRM);
            f[2] = f2bf(p0.z * NRM); f[3] = f2bf(p0.w * NRM);
            f[4] = f2bf(p1.x * NRM); f[5] = f2bf(p1.y * NRM);
            f[6] = f2bf(p1.z * NRM); f[7] = f2bf(p1.w * NRM);
            pb[ks][mt] = f;
        }
}

// ---------------- Kernel A: kv += K'^T V, ksum += colsum(K') ----------------
// EXACT R0 body (verified 101.8us at grid 512).
__global__ __launch_bounds__(256, 2) void kv_kernel(
    const float* __restrict__ kin, const float* __restrict__ vin,
    const float* __restrict__ Pm, float* __restrict__ kv, float* __restrict__ ksum)
{
    __shared__ short Kb[32 * 72];    // K tile bf16 [l][d], stride 72
    __shared__ short Vt[64 * 40];    // V^T tile   [d][l], stride 40
    __shared__ short Ktp[256 * 40];  // K'^T tile  [m][l], stride 40
    __shared__ float cl_lds[32];     // eps - 0.5*NRM^2*|k|^2 per row

    const int t = threadIdx.x;
    const int lane = t & 63, wv = t >> 6;
    const int quad = lane >> 4, l16 = lane & 15;
    const int bh = blockIdx.x >> 4, chunk = blockIdx.x & 15;

    bf16x8 pb[2][4];
    load_pfrags(Pm, wv, quad, l16, pb);

    f32x4 kvacc[4][4];
#pragma unroll
    for (int mt = 0; mt < 4; ++mt)
#pragma unroll
        for (int dt = 0; dt < 4; ++dt) kvacc[mt][dt] = (f32x4)0.f;
    float ksacc[4] = {0.f, 0.f, 0.f, 0.f};

    const size_t base = ((size_t)bh * LL + (size_t)chunk * 512) * DD;
    const float* kb = kin + base;
    const float* vb = vin + base;
    const int sl = t >> 4, sd4 = t & 15;

    for (int tile = 0; tile < 16; ++tile) {
        __syncthreads();
        // --- stage: K -> Kb (bf16), V -> Vt (transposed bf16), row norms ---
#pragma unroll
        for (int half = 0; half < 2; ++half) {
            const int l = sl + half * 16;
            const int gi = (tile * 32 + l) * DD + sd4 * 4;
            float4 kf = *(const float4*)(kb + gi);
            float sq = kf.x * kf.x + kf.y * kf.y + kf.z * kf.z + kf.w * kf.w;
            sq += __shfl_xor(sq, 1); sq += __shfl_xor(sq, 2);
            sq += __shfl_xor(sq, 4); sq += __shfl_xor(sq, 8);
            if (sd4 == 0) cl_lds[l] = EPSK - SQS * sq;
            union { short s[4]; unsigned long long u; } uk;
            uk.s[0] = f2bf(kf.x); uk.s[1] = f2bf(kf.y);
            uk.s[2] = f2bf(kf.z); uk.s[3] = f2bf(kf.w);
            *(unsigned long long*)&Kb[l * 72 + sd4 * 4] = uk.u;
            float4 vf = *(const float4*)(vb + gi);
            Vt[(sd4 * 4 + 0) * 40 + l] = f2bf(vf.x);
            Vt[(sd4 * 4 + 1) * 40 + l] = f2bf(vf.y);
            Vt[(sd4 * 4 + 2) * 40 + l] = f2bf(vf.z);
            Vt[(sd4 * 4 + 3) * 40 + l] = f2bf(vf.w);
        }
        __syncthreads();
        // --- proj MFMA: pt[lt][mt] = (K*NRM) P^T, wave owns m-chunk 64*wv ---
        f32x4 pt[2][4];
#pragma unroll
        for (int lt = 0; lt < 2; ++lt)
#pragma unroll
            for (int mt = 0; mt < 4; ++mt) pt[lt][mt] = (f32x4)0.f;
#pragma unroll
        for (int ks = 0; ks < 2; ++ks)
#pragma unroll
            for (int lt = 0; lt < 2; ++lt) {
                bf16x8 af = *(bf16x8*)&Kb[(lt * 16 + l16) * 72 + ks * 32 + quad * 8];
#pragma unroll
                for (int mt = 0; mt < 4; ++mt)
                    pt[lt][mt] = MFMA(af, pb[ks][mt], pt[lt][mt]);
            }
        // --- exp -> K', accumulate ksum, write K'^T[m][l] (b64, l-contig) ---
        float cl[2][4];
#pragma unroll
        for (int lt = 0; lt < 2; ++lt)
#pragma unroll
            for (int r = 0; r < 4; ++r) cl[lt][r] = cl_lds[lt * 16 + quad * 4 + r];
#pragma unroll
        for (int lt = 0; lt < 2; ++lt)
#pragma unroll
            for (int mt = 0; mt < 4; ++mt) {
                union { short s[4]; unsigned long long u; } uo;
#pragma unroll
                for (int r = 0; r < 4; ++r) {
                    float w = __expf(pt[lt][mt][r] + cl[lt][r]);
                    ksacc[mt] += w;
                    uo.s[r] = f2bf(w);
                }
                *(unsigned long long*)&Ktp[(wv * 64 + mt * 16 + l16) * 40 + lt * 16 + quad * 4] = uo.u;
            }
        // --- kv MFMA: kv[m][d] += sum_l K'^T[m][l] V[l][d], K = 32 = one step ---
        bf16x8 aK[4], bV[4];
#pragma unroll
        for (int mt = 0; mt < 4; ++mt)
            aK[mt] = *(bf16x8*)&Ktp[(wv * 64 + mt * 16 + l16) * 40 + quad * 8];
#pragma unroll
        for (int dt = 0; dt < 4; ++dt)
            bV[dt] = *(bf16x8*)&Vt[(dt * 16 + l16) * 40 + quad * 8];
#pragma unroll
        for (int mt = 0; mt < 4; ++mt)
#pragma unroll
            for (int dt = 0; dt < 4; ++dt)
                kvacc[mt][dt] = MFMA(aK[mt], bV[dt], kvacc[mt][dt]);
    }
    // --- epilogue: atomics into workspace ---
    float* kvg = kv + (size_t)bh * MM * DD;
#pragma unroll
    for (int mt = 0; mt < 4; ++mt) {
        float r = ksacc[mt];
        r += __shfl_xor(r, 16); r += __shfl_xor(r, 32);
        if (quad == 0) atomicAdd(ksum + bh * MM + wv * 64 + mt * 16 + l16, r);
#pragma unroll
        for (int dt = 0; dt < 4; ++dt)
#pragma unroll
            for (int rg = 0; rg < 4; ++rg)
                atomicAdd(kvg + (wv * 64 + mt * 16 + quad * 4 + rg) * DD + dt * 16 + l16,
                          kvacc[mt][dt][rg]);
    }
}

// ---------------- Kernel B: out = (Q' kv) * z ------------------------------
// EXACT R2 body (verified pass at grid 1024).
__global__ __launch_bounds__(256, 4) void out_kernel(
    const float* __restrict__ qin, const float* __restrict__ Pm,
    const float* __restrict__ kv, const float* __restrict__ ksum,
    float* __restrict__ out)
{
    __shared__ short sm[64 * 264];    // kv^T staging [d][m], then Q' tile [32][264]
    __shared__ short Qb[32 * 72];     // Q tile bf16 [l][d]
    __shared__ float ks_lds[MM];
    __shared__ float cl_lds[32];
    __shared__ float z_lds[32];

    const int t = threadIdx.x;
    const int lane = t & 63, wv = t >> 6;
    const int quad = lane >> 4, l16 = lane & 15;
    int bh, chunk;
    decode_block(blockIdx.x, bh, chunk);

    bf16x8 pb[2][4];
    load_pfrags(Pm, wv, quad, l16, pb);

    // --- stage kv^T (bf16 transposed) + ksum, once per block ---
    const float* kvg = kv + (size_t)bh * MM * DD;
#pragma unroll
    for (int it = 0; it < 16; ++it) {
        const int i = t + it * 256;          // float4 index over [256][16]
        const int m = i >> 4, d4 = i & 15;
        const float4 f = *(const float4*)(kvg + m * DD + d4 * 4);
        sm[(d4 * 4 + 0) * 264 + m] = f2bf(f.x);
        sm[(d4 * 4 + 1) * 264 + m] = f2bf(f.y);
        sm[(d4 * 4 + 2) * 264 + m] = f2bf(f.z);
        sm[(d4 * 4 + 3) * 264 + m] = f2bf(f.w);
    }
    ks_lds[t] = ksum[bh * MM + t];
    __syncthreads();

    // --- hoist kv^T fragments to registers (frees sm for Q') ---
    bf16x8 bk[8];
#pragma unroll
    for (int ks = 0; ks < 8; ++ks)
        bk[ks] = *(const bf16x8*)&sm[(wv * 16 + l16) * 264 + ks * 32 + quad * 8];

    const size_t base = ((size_t)bh * LL + (size_t)chunk * RPB) * DD;
    const float* qb = qin + base;
    float* ob = out + base;
    const int sl = t >> 4, sd4 = t & 15;

    float4 qreg[2];
#pragma unroll
    for (int half = 0; half < 2; ++half)
        qreg[half] = *(const float4*)(qb + (sl + half * 16) * DD + sd4 * 4);

    for (int tile = 0; tile < NTILE; ++tile) {
        __syncthreads();   // bk hoist / prev-tile sm+z reads complete
        if (t < 32) z_lds[t] = 0.f;
#pragma unroll
        for (int half = 0; half < 2; ++half) {
            const int l = sl + half * 16;
            const float4 qf = qreg[half];
            float sq = qf.x * qf.x + qf.y * qf.y + qf.z * qf.z + qf.w * qf.w;
            sq += __shfl_xor(sq, 1); sq += __shfl_xor(sq, 2);
            sq += __shfl_xor(sq, 4); sq += __shfl_xor(sq, 8);
            if (sd4 == 0) cl_lds[l] = EPSK - SQS * sq;
            union { short s[4]; unsigned long long u; } uq;
            uq.s[0] = f2bf(qf.x); uq.s[1] = f2bf(qf.y);
            uq.s[2] = f2bf(qf.z); uq.s[3] = f2bf(qf.w);
            *(unsigned long long*)&Qb[l * 72 + sd4 * 4] = uq.u;
        }
        if (tile + 1 < NTILE) {
#pragma unroll
            for (int half = 0; half < 2; ++half)
                qreg[half] = *(const float4*)(qb + ((tile + 1) * 32 + sl + half * 16) * DD + sd4 * 4);
        }
        __syncthreads();

        // --- proj MFMA, SWAPPED operands: A=P-frags, B=Q-frags -> P'[m][l].
        // Lane (quad,l16) reg r holds proj[m=wv*64+mt*16+quad*4+r][l=lt*16+l16]
        // -> exp output is m-contiguous per lane -> b64 Q'[l][m] stores.
        bf16x8 qf2[2][2];
#pragma unroll
        for (int ks2 = 0; ks2 < 2; ++ks2)
#pragma unroll
            for (int lt = 0; lt < 2; ++lt)
                qf2[ks2][lt] = *(const bf16x8*)&Qb[(lt * 16 + l16) * 72 + ks2 * 32 + quad * 8];
        const float clv0 = cl_lds[l16];
        const float clv1 = cl_lds[16 + l16];
        float zp0 = 0.f, zp1 = 0.f;
#pragma unroll
        for (int mt = 0; mt < 4; ++mt) {
            f32x4 pt0 = (f32x4)0.f, pt1 = (f32x4)0.f;
#pragma unroll
            for (int ks2 = 0; ks2 < 2; ++ks2) {
                pt0 = MFMA(pb[ks2][mt], qf2[ks2][0], pt0);
                pt1 = MFMA(pb[ks2][mt], qf2[ks2][1], pt1);
            }
            const float4 km4 = *(const float4*)&ks_lds[wv * 64 + mt * 16 + quad * 4];
            const float km[4] = {km4.x, km4.y, km4.z, km4.w};
            union { short s[4]; unsigned long long u; } u0, u1;
#pragma unroll
            for (int r = 0; r < 4; ++r) {
                const float w0 = __expf(pt0[r] + clv0);
                const float w1 = __expf(pt1[r] + clv1);
                zp0 += w0 * km[r];
                zp1 += w1 * km[r];
                u0.s[r] = f2bf(w0);
                u1.s[r] = f2bf(w1);
            }
            *(unsigned long long*)&sm[(l16) * 264 + wv * 64 + mt * 16 + quad * 4] = u0.u;
            *(unsigned long long*)&sm[(16 + l16) * 264 + wv * 64 + mt * 16 + quad * 4] = u1.u;
        }
        // z: lane covers 16 m-values; reduce over quads, cross-wave LDS atomic
        zp0 += __shfl_xor(zp0, 16); zp0 += __shfl_xor(zp0, 32);
        zp1 += __shfl_xor(zp1, 16); zp1 += __shfl_xor(zp1, 32);
        if (lane < 16) {
            atomicAdd(&z_lds[l16], zp0);
            atomicAdd(&z_lds[16 + l16], zp1);
        }
        __syncthreads();

        // --- out MFMA: out[l][d] = sum_m Q'[l][m] kv[m][d]; kv frags in regs ---
        f32x4 oc0 = (f32x4)0.f, oc1 = (f32x4)0.f;
#pragma unroll
        for (int ks = 0; ks < 8; ++ks) {
            const bf16x8 aq0 = *(const bf16x8*)&sm[(l16) * 264 + ks * 32 + quad * 8];
            const bf16x8 aq1 = *(const bf16x8*)&sm[(16 + l16) * 264 + ks * 32 + quad * 8];
            oc0 = MFMA(aq0, bk[ks], oc0);
            oc1 = MFMA(aq1, bk[ks], oc1);
        }
#pragma unroll
        for (int r = 0; r < 4; ++r) {
            const int row0 = quad * 4 + r;
            const float z0 = 1.f / (z_lds[row0] + EPSZ);
            ob[(size_t)(tile * 32 + row0) * DD + wv * 16 + l16] = oc0[r] * z0;
            const int row1 = 16 + quad * 4 + r;
            const float z1 = 1.f / (z_lds[row1] + EPSZ);
            ob[(size_t)(tile * 32 + row1) * DD + wv * 16 + l16] = oc1[r] * z1;
        }
    }
}

extern "C" void kernel_launch(void* const* d_in, const int* in_sizes, int n_in,
                              void* d_out, int out_size, void* d_ws, size_t ws_size,
                              hipStream_t stream) {
    const float* q  = (const float*)d_in[0];
    const float* k  = (const float*)d_in[1];
    const float* v  = (const float*)d_in[2];
    const float* Pm = (const float*)d_in[3];

    float* kvw = (float*)d_ws;                       // [BH, M, D]
    float* ksw = kvw + (size_t)BH * MM * DD;         // [BH, M]

    hipMemsetAsync(d_ws, 0, ((size_t)BH * MM * DD + (size_t)BH * MM) * sizeof(float), stream);
    hipLaunchKernelGGL(kv_kernel, dim3(512), dim3(256), 0, stream, k, v, Pm, kvw, ksw);
    hipLaunchKernelGGL(out_kernel, dim3(1024), dim3(256), 0, stream, q, Pm, kvw, ksw, (float*)d_out);
}

// Round 7
// 293.036 us; speedup vs baseline: 1.3632x; 1.1159x over previous
//
#include <hip/hip_runtime.h>
#include <hip/hip_bf16.h>

// Performer (FAVOR+) attention, bf16-MFMA two-pass. b=4 h=8 L=8192 d=64 m=256.
// R7: kv accumulation made ATOMIC-FREE. Evidence: R2 showed +16.7M atomics =>
// +90us; kv_kernel is 75% stall at 19% occupancy, and the 16-way-contended
// device-scope atomicAdd epilogue is the only component that can absorb the
// unaccounted ~50us. Each block now stores a private kv/ksum partial (plain
// coalesced stores, no memset needed); a small reduce kernel (L3-warm reads)
// produces final kv/ksum. Also: prefetch ISSUE moved to after the post-stage
// barrier (R1 placed it before => drained immediately; now it overlaps the
// ~600cy MFMA+exp phase). out_kernel = exact R2/R6 verified body @1024.
// ws-gated: if ws_size < 36.2MB, fall back to the exact verified R6 path.

#define BH 32
#define LL 8192
#define DD 64
#define MM 256
#define NRM 0.35355339059327373f   // 64^-0.25
#define SQS 0.0625f                // 0.5*NRM^2
#define EPSK 1e-6f
#define EPSZ 1e-6f
#define NTILE 8                    // out_kernel: 32-row tiles per block
#define RPB 256                    // out_kernel: rows per block

// partial-path ws layout (floats)
#define NBLK_A 512
#define KVP_SZ ((size_t)NBLK_A * MM * DD)     // 8388608 (32 MB)
#define KSP_SZ ((size_t)NBLK_A * MM)          // 131072  (0.5 MB)
#define KVF_SZ ((size_t)BH * MM * DD)         // 524288  (2 MB)
#define KSF_SZ ((size_t)BH * MM)              // 8192
#define WS_NEED_BYTES ((KVP_SZ + KSP_SZ + KVF_SZ + KSF_SZ) * sizeof(float))

typedef __attribute__((ext_vector_type(8))) short bf16x8;
typedef __attribute__((ext_vector_type(4))) float f32x4;
#define MFMA(a, b, c) __builtin_amdgcn_mfma_f32_16x16x32_bf16(a, b, c, 0, 0, 0)

static __device__ __forceinline__ short f2bf(float x) {
    union { float f; unsigned u; } c{x};
    unsigned r = c.u + 0x7fffu + ((c.u >> 16) & 1u);   // RNE
    return (short)(r >> 16);
}

static __device__ __forceinline__ void decode_block(int i, int& bh, int& chunk) {
    bh = ((i & 7) << 2) | ((i >> 3) & 3);
    chunk = i >> 5;
}

// P fragments (NRM folded): elem jj = P[64*wv + mt*16 + l16][ks*32 + quad*8 + jj]*NRM
static __device__ __forceinline__ void load_pfrags(
    const float* __restrict__ Pm, int wv, int quad, int l16, bf16x8 pb[2][4])
{
#pragma unroll
    for (int ks = 0; ks < 2; ++ks)
#pragma unroll
        for (int mt = 0; mt < 4; ++mt) {
            const float* pr = Pm + (wv * 64 + mt * 16 + l16) * DD + ks * 32 + quad * 8;
            float4 p0 = *(const float4*)pr;
            float4 p1 = *(const float4*)(pr + 4);
            bf16x8 f;
            f[0] = f2bf(p0.x * NRM); f[1] = f2bf(p0.y * NRM);
            f[2] = f2bf(p0.z * NRM); f[3] = f2bf(p0.w * NRM);
            f[4] = f2bf(p1.x * NRM); f[5] = f2bf(p1.y * NRM);
            f[6] = f2bf(p1.z * NRM); f[7] = f2bf(p1.w * NRM);
            pb[ks][mt] = f;
        }
}

// ============ shared tile body for kv pass (template over epilogue) =========
// kv_partial: R6 kv body + post-barrier prefetch + plain-store epilogue.
__global__ __launch_bounds__(256, 2) void kv_partial_kernel(
    const float* __restrict__ kin, const float* __restrict__ vin,
    const float* __restrict__ Pm, float* __restrict__ kvp, float* __restrict__ ksp)
{
    __shared__ short Kb[32 * 72];    // K tile bf16 [l][d], stride 72
    __shared__ short Vt[64 * 40];    // V^T tile   [d][l], stride 40
    __shared__ short Ktp[256 * 40];  // K'^T tile  [m][l], stride 40
    __shared__ float cl_lds[32];

    const int t = threadIdx.x;
    const int lane = t & 63, wv = t >> 6;
    const int quad = lane >> 4, l16 = lane & 15;
    const int bh = blockIdx.x >> 4, chunk = blockIdx.x & 15;

    bf16x8 pb[2][4];
    load_pfrags(Pm, wv, quad, l16, pb);

    f32x4 kvacc[4][4];
#pragma unroll
    for (int mt = 0; mt < 4; ++mt)
#pragma unroll
        for (int dt = 0; dt < 4; ++dt) kvacc[mt][dt] = (f32x4)0.f;
    float ksacc[4] = {0.f, 0.f, 0.f, 0.f};

    const size_t base = ((size_t)bh * LL + (size_t)chunk * 512) * DD;
    const float* kb = kin + base;
    const float* vb = vin + base;
    const int sl = t >> 4, sd4 = t & 15;

    // prologue: tile-0 loads
    float4 kreg[2], vreg[2];
#pragma unroll
    for (int half = 0; half < 2; ++half) {
        const int gi = (sl + half * 16) * DD + sd4 * 4;
        kreg[half] = *(const float4*)(kb + gi);
        vreg[half] = *(const float4*)(vb + gi);
    }

    for (int tile = 0; tile < 16; ++tile) {
        __syncthreads();   // L1: prev MFMA done with LDS; drains prefetch loads
        // --- stage prefetched regs -> LDS (bf16), row norms ---
#pragma unroll
        for (int half = 0; half < 2; ++half) {
            const int l = sl + half * 16;
            const float4 kf = kreg[half];
            const float4 vf = vreg[half];
            float sq = kf.x * kf.x + kf.y * kf.y + kf.z * kf.z + kf.w * kf.w;
            sq += __shfl_xor(sq, 1); sq += __shfl_xor(sq, 2);
            sq += __shfl_xor(sq, 4); sq += __shfl_xor(sq, 8);
            if (sd4 == 0) cl_lds[l] = EPSK - SQS * sq;
            union { short s[4]; unsigned long long u; } uk;
            uk.s[0] = f2bf(kf.x); uk.s[1] = f2bf(kf.y);
            uk.s[2] = f2bf(kf.z); uk.s[3] = f2bf(kf.w);
            *(unsigned long long*)&Kb[l * 72 + sd4 * 4] = uk.u;
            Vt[(sd4 * 4 + 0) * 40 + l] = f2bf(vf.x);
            Vt[(sd4 * 4 + 1) * 40 + l] = f2bf(vf.y);
            Vt[(sd4 * 4 + 2) * 40 + l] = f2bf(vf.z);
            Vt[(sd4 * 4 + 3) * 40 + l] = f2bf(vf.w);
        }
        __syncthreads();   // L2: LDS tile visible
        // --- issue next tile's loads AFTER L2: latency overlaps MFMA+exp,
        //     drained at next iteration's L1 ---
        if (tile + 1 < 16) {
#pragma unroll
            for (int half = 0; half < 2; ++half) {
                const int gi = ((tile + 1) * 32 + sl + half * 16) * DD + sd4 * 4;
                kreg[half] = *(const float4*)(kb + gi);
                vreg[half] = *(const float4*)(vb + gi);
            }
        }
        // --- proj MFMA: pt[lt][mt] = (K*NRM) P^T ---
        f32x4 pt[2][4];
#pragma unroll
        for (int lt = 0; lt < 2; ++lt)
#pragma unroll
            for (int mt = 0; mt < 4; ++mt) pt[lt][mt] = (f32x4)0.f;
#pragma unroll
        for (int ks = 0; ks < 2; ++ks)
#pragma unroll
            for (int lt = 0; lt < 2; ++lt) {
                bf16x8 af = *(bf16x8*)&Kb[(lt * 16 + l16) * 72 + ks * 32 + quad * 8];
#pragma unroll
                for (int mt = 0; mt < 4; ++mt)
                    pt[lt][mt] = MFMA(af, pb[ks][mt], pt[lt][mt]);
            }
        // --- exp -> K', ksum partials, write K'^T[m][l] ---
        float cl[2][4];
#pragma unroll
        for (int lt = 0; lt < 2; ++lt)
#pragma unroll
            for (int r = 0; r < 4; ++r) cl[lt][r] = cl_lds[lt * 16 + quad * 4 + r];
#pragma unroll
        for (int lt = 0; lt < 2; ++lt)
#pragma unroll
            for (int mt = 0; mt < 4; ++mt) {
                union { short s[4]; unsigned long long u; } uo;
#pragma unroll
                for (int r = 0; r < 4; ++r) {
                    float w = __expf(pt[lt][mt][r] + cl[lt][r]);
                    ksacc[mt] += w;
                    uo.s[r] = f2bf(w);
                }
                *(unsigned long long*)&Ktp[(wv * 64 + mt * 16 + l16) * 40 + lt * 16 + quad * 4] = uo.u;
            }
        // --- kv MFMA ---
        bf16x8 aK[4], bV[4];
#pragma unroll
        for (int mt = 0; mt < 4; ++mt)
            aK[mt] = *(bf16x8*)&Ktp[(wv * 64 + mt * 16 + l16) * 40 + quad * 8];
#pragma unroll
        for (int dt = 0; dt < 4; ++dt)
            bV[dt] = *(bf16x8*)&Vt[(dt * 16 + l16) * 40 + quad * 8];
#pragma unroll
        for (int mt = 0; mt < 4; ++mt)
#pragma unroll
            for (int dt = 0; dt < 4; ++dt)
                kvacc[mt][dt] = MFMA(aK[mt], bV[dt], kvacc[mt][dt]);
    }
    // --- epilogue: plain stores to private partial slab (no contention) ---
    float* kvb = kvp + (size_t)blockIdx.x * (MM * DD);
#pragma unroll
    for (int mt = 0; mt < 4; ++mt) {
        float r = ksacc[mt];
        r += __shfl_xor(r, 16); r += __shfl_xor(r, 32);
        if (quad == 0) ksp[blockIdx.x * MM + wv * 64 + mt * 16 + l16] = r;
#pragma unroll
        for (int dt = 0; dt < 4; ++dt)
#pragma unroll
            for (int rg = 0; rg < 4; ++rg)
                kvb[(wv * 64 + mt * 16 + quad * 4 + rg) * DD + dt * 16 + l16] =
                    kvacc[mt][dt][rg];
    }
}

// ---- reduce: kv[bh] = sum_c kvp[bh*16+c], ksum[bh] = sum_c ksp[bh*16+c] ----
__global__ __launch_bounds__(256, 2) void reduce_kernel(
    const float* __restrict__ kvp, const float* __restrict__ ksp,
    float* __restrict__ kvf, float* __restrict__ ksf)
{
    const int t = threadIdx.x;
    const int bh = blockIdx.x >> 4, s = blockIdx.x & 15;
    const int i = s * 1024 + t * 4;          // float idx within [256*64]
    float4 acc = make_float4(0.f, 0.f, 0.f, 0.f);
#pragma unroll
    for (int c = 0; c < 16; ++c) {
        const float4 p = *(const float4*)&kvp[((size_t)(bh * 16 + c)) * (MM * DD) + i];
        acc.x += p.x; acc.y += p.y; acc.z += p.z; acc.w += p.w;
    }
    *(float4*)&kvf[(size_t)bh * (MM * DD) + i] = acc;
    if (s == 0) {
        float a = 0.f;
#pragma unroll
        for (int c = 0; c < 16; ++c) a += ksp[(bh * 16 + c) * MM + t];
        ksf[bh * MM + t] = a;
    }
}

// ---------------- Kernel A (fallback): atomic epilogue, exact R6 ------------
__global__ __launch_bounds__(256, 2) void kv_kernel(
    const float* __restrict__ kin, const float* __restrict__ vin,
    const float* __restrict__ Pm, float* __restrict__ kv, float* __restrict__ ksum)
{
    __shared__ short Kb[32 * 72];
    __shared__ short Vt[64 * 40];
    __shared__ short Ktp[256 * 40];
    __shared__ float cl_lds[32];

    const int t = threadIdx.x;
    const int lane = t & 63, wv = t >> 6;
    const int quad = lane >> 4, l16 = lane & 15;
    const int bh = blockIdx.x >> 4, chunk = blockIdx.x & 15;

    bf16x8 pb[2][4];
    load_pfrags(Pm, wv, quad, l16, pb);

    f32x4 kvacc[4][4];
#pragma unroll
    for (int mt = 0; mt < 4; ++mt)
#pragma unroll
        for (int dt = 0; dt < 4; ++dt) kvacc[mt][dt] = (f32x4)0.f;
    float ksacc[4] = {0.f, 0.f, 0.f, 0.f};

    const size_t base = ((size_t)bh * LL + (size_t)chunk * 512) * DD;
    const float* kb = kin + base;
    const float* vb = vin + base;
    const int sl = t >> 4, sd4 = t & 15;

    for (int tile = 0; tile < 16; ++tile) {
        __syncthreads();
#pragma unroll
        for (int half = 0; half < 2; ++half) {
            const int l = sl + half * 16;
            const int gi = (tile * 32 + l) * DD + sd4 * 4;
            float4 kf = *(const float4*)(kb + gi);
            float sq = kf.x * kf.x + kf.y * kf.y + kf.z * kf.z + kf.w * kf.w;
            sq += __shfl_xor(sq, 1); sq += __shfl_xor(sq, 2);
            sq += __shfl_xor(sq, 4); sq += __shfl_xor(sq, 8);
            if (sd4 == 0) cl_lds[l] = EPSK - SQS * sq;
            union { short s[4]; unsigned long long u; } uk;
            uk.s[0] = f2bf(kf.x); uk.s[1] = f2bf(kf.y);
            uk.s[2] = f2bf(kf.z); uk.s[3] = f2bf(kf.w);
            *(unsigned long long*)&Kb[l * 72 + sd4 * 4] = uk.u;
            float4 vf = *(const float4*)(vb + gi);
            Vt[(sd4 * 4 + 0) * 40 + l] = f2bf(vf.x);
            Vt[(sd4 * 4 + 1) * 40 + l] = f2bf(vf.y);
            Vt[(sd4 * 4 + 2) * 40 + l] = f2bf(vf.z);
            Vt[(sd4 * 4 + 3) * 40 + l] = f2bf(vf.w);
        }
        __syncthreads();
        f32x4 pt[2][4];
#pragma unroll
        for (int lt = 0; lt < 2; ++lt)
#pragma unroll
            for (int mt = 0; mt < 4; ++mt) pt[lt][mt] = (f32x4)0.f;
#pragma unroll
        for (int ks = 0; ks < 2; ++ks)
#pragma unroll
            for (int lt = 0; lt < 2; ++lt) {
                bf16x8 af = *(bf16x8*)&Kb[(lt * 16 + l16) * 72 + ks * 32 + quad * 8];
#pragma unroll
                for (int mt = 0; mt < 4; ++mt)
                    pt[lt][mt] = MFMA(af, pb[ks][mt], pt[lt][mt]);
            }
        float cl[2][4];
#pragma unroll
        for (int lt = 0; lt < 2; ++lt)
#pragma unroll
            for (int r = 0; r < 4; ++r) cl[lt][r] = cl_lds[lt * 16 + quad * 4 + r];
#pragma unroll
        for (int lt = 0; lt < 2; ++lt)
#pragma unroll
            for (int mt = 0; mt < 4; ++mt) {
                union { short s[4]; unsigned long long u; } uo;
#pragma unroll
                for (int r = 0; r < 4; ++r) {
                    float w = __expf(pt[lt][mt][r] + cl[lt][r]);
                    ksacc[mt] += w;
                    uo.s[r] = f2bf(w);
                }
                *(unsigned long long*)&Ktp[(wv * 64 + mt * 16 + l16) * 40 + lt * 16 + quad * 4] = uo.u;
            }
        bf16x8 aK[4], bV[4];
#pragma unroll
        for (int mt = 0; mt < 4; ++mt)
            aK[mt] = *(bf16x8*)&Ktp[(wv * 64 + mt * 16 + l16) * 40 + quad * 8];
#pragma unroll
        for (int dt = 0; dt < 4; ++dt)
            bV[dt] = *(bf16x8*)&Vt[(dt * 16 + l16) * 40 + quad * 8];
#pragma unroll
        for (int mt = 0; mt < 4; ++mt)
#pragma unroll
            for (int dt = 0; dt < 4; ++dt)
                kvacc[mt][dt] = MFMA(aK[mt], bV[dt], kvacc[mt][dt]);
    }
    float* kvg = kv + (size_t)bh * MM * DD;
#pragma unroll
    for (int mt = 0; mt < 4; ++mt) {
        float r = ksacc[mt];
        r += __shfl_xor(r, 16); r += __shfl_xor(r, 32);
        if (quad == 0) atomicAdd(ksum + bh * MM + wv * 64 + mt * 16 + l16, r);
#pragma unroll
        for (int dt = 0; dt < 4; ++dt)
#pragma unroll
            for (int rg = 0; rg < 4; ++rg)
                atomicAdd(kvg + (wv * 64 + mt * 16 + quad * 4 + rg) * DD + dt * 16 + l16,
                          kvacc[mt][dt][rg]);
    }
}

// ---------------- Kernel B: out = (Q' kv) * z — EXACT R2/R6 verified body ---
__global__ __launch_bounds__(256, 4) void out_kernel(
    const float* __restrict__ qin, const float* __restrict__ Pm,
    const float* __restrict__ kv, const float* __restrict__ ksum,
    float* __restrict__ out)
{
    __shared__ short sm[64 * 264];
    __shared__ short Qb[32 * 72];
    __shared__ float ks_lds[MM];
    __shared__ float cl_lds[32];
    __shared__ float z_lds[32];

    const int t = threadIdx.x;
    const int lane = t & 63, wv = t >> 6;
    const int quad = lane >> 4, l16 = lane & 15;
    int bh, chunk;
    decode_block(blockIdx.x, bh, chunk);

    bf16x8 pb[2][4];
    load_pfrags(Pm, wv, quad, l16, pb);

    const float* kvg = kv + (size_t)bh * MM * DD;
#pragma unroll
    for (int it = 0; it < 16; ++it) {
        const int i = t + it * 256;
        const int m = i >> 4, d4 = i & 15;
        const float4 f = *(const float4*)(kvg + m * DD + d4 * 4);
        sm[(d4 * 4 + 0) * 264 + m] = f2bf(f.x);
        sm[(d4 * 4 + 1) * 264 + m] = f2bf(f.y);
        sm[(d4 * 4 + 2) * 264 + m] = f2bf(f.z);
        sm[(d4 * 4 + 3) * 264 + m] = f2bf(f.w);
    }
    ks_lds[t] = ksum[bh * MM + t];
    __syncthreads();

    bf16x8 bk[8];
#pragma unroll
    for (int ks = 0; ks < 8; ++ks)
        bk[ks] = *(const bf16x8*)&sm[(wv * 16 + l16) * 264 + ks * 32 + quad * 8];

    const size_t base = ((size_t)bh * LL + (size_t)chunk * RPB) * DD;
    const float* qb = qin + base;
    float* ob = out + base;
    const int sl = t >> 4, sd4 = t & 15;

    float4 qreg[2];
#pragma unroll
    for (int half = 0; half < 2; ++half)
        qreg[half] = *(const float4*)(qb + (sl + half * 16) * DD + sd4 * 4);

    for (int tile = 0; tile < NTILE; ++tile) {
        __syncthreads();
        if (t < 32) z_lds[t] = 0.f;
#pragma unroll
        for (int half = 0; half < 2; ++half) {
            const int l = sl + half * 16;
            const float4 qf = qreg[half];
            float sq = qf.x * qf.x + qf.y * qf.y + qf.z * qf.z + qf.w * qf.w;
            sq += __shfl_xor(sq, 1); sq += __shfl_xor(sq, 2);
            sq += __shfl_xor(sq, 4); sq += __shfl_xor(sq, 8);
            if (sd4 == 0) cl_lds[l] = EPSK - SQS * sq;
            union { short s[4]; unsigned long long u; } uq;
            uq.s[0] = f2bf(qf.x); uq.s[1] = f2bf(qf.y);
            uq.s[2] = f2bf(qf.z); uq.s[3] = f2bf(qf.w);
            *(unsigned long long*)&Qb[l * 72 + sd4 * 4] = uq.u;
        }
        if (tile + 1 < NTILE) {
#pragma unroll
            for (int half = 0; half < 2; ++half)
                qreg[half] = *(const float4*)(qb + ((tile + 1) * 32 + sl + half * 16) * DD + sd4 * 4);
        }
        __syncthreads();

        bf16x8 qf2[2][2];
#pragma unroll
        for (int ks2 = 0; ks2 < 2; ++ks2)
#pragma unroll
            for (int lt = 0; lt < 2; ++lt)
                qf2[ks2][lt] = *(const bf16x8*)&Qb[(lt * 16 + l16) * 72 + ks2 * 32 + quad * 8];
        const float clv0 = cl_lds[l16];
        const float clv1 = cl_lds[16 + l16];
        float zp0 = 0.f, zp1 = 0.f;
#pragma unroll
        for (int mt = 0; mt < 4; ++mt) {
            f32x4 pt0 = (f32x4)0.f, pt1 = (f32x4)0.f;
#pragma unroll
            for (int ks2 = 0; ks2 < 2; ++ks2) {
                pt0 = MFMA(pb[ks2][mt], qf2[ks2][0], pt0);
                pt1 = MFMA(pb[ks2][mt], qf2[ks2][1], pt1);
            }
            const float4 km4 = *(const float4*)&ks_lds[wv * 64 + mt * 16 + quad * 4];
            const float km[4] = {km4.x, km4.y, km4.z, km4.w};
            union { short s[4]; unsigned long long u; } u0, u1;
#pragma unroll
            for (int r = 0; r < 4; ++r) {
                const float w0 = __expf(pt0[r] + clv0);
                const float w1 = __expf(pt1[r] + clv1);
                zp0 += w0 * km[r];
                zp1 += w1 * km[r];
                u0.s[r] = f2bf(w0);
                u1.s[r] = f2bf(w1);
            }
            *(unsigned long long*)&sm[(l16) * 264 + wv * 64 + mt * 16 + quad * 4] = u0.u;
            *(unsigned long long*)&sm[(16 + l16) * 264 + wv * 64 + mt * 16 + quad * 4] = u1.u;
        }
        zp0 += __shfl_xor(zp0, 16); zp0 += __shfl_xor(zp0, 32);
        zp1 += __shfl_xor(zp1, 16); zp1 += __shfl_xor(zp1, 32);
        if (lane < 16) {
            atomicAdd(&z_lds[l16], zp0);
            atomicAdd(&z_lds[16 + l16], zp1);
        }
        __syncthreads();

        f32x4 oc0 = (f32x4)0.f, oc1 = (f32x4)0.f;
#pragma unroll
        for (int ks = 0; ks < 8; ++ks) {
            const bf16x8 aq0 = *(const bf16x8*)&sm[(l16) * 264 + ks * 32 + quad * 8];
            const bf16x8 aq1 = *(const bf16x8*)&sm[(16 + l16) * 264 + ks * 32 + quad * 8];
            oc0 = MFMA(aq0, bk[ks], oc0);
            oc1 = MFMA(aq1, bk[ks], oc1);
        }
#pragma unroll
        for (int r = 0; r < 4; ++r) {
            const int row0 = quad * 4 + r;
            const float z0 = 1.f / (z_lds[row0] + EPSZ);
            ob[(size_t)(tile * 32 + row0) * DD + wv * 16 + l16] = oc0[r] * z0;
            const int row1 = 16 + quad * 4 + r;
            const float z1 = 1.f / (z_lds[row1] + EPSZ);
            ob[(size_t)(tile * 32 + row1) * DD + wv * 16 + l16] = oc1[r] * z1;
        }
    }
}

extern "C" void kernel_launch(void* const* d_in, const int* in_sizes, int n_in,
                              void* d_out, int out_size, void* d_ws, size_t ws_size,
                              hipStream_t stream) {
    const float* q  = (const float*)d_in[0];
    const float* k  = (const float*)d_in[1];
    const float* v  = (const float*)d_in[2];
    const float* Pm = (const float*)d_in[3];

    if (ws_size >= WS_NEED_BYTES) {
        // atomic-free path: partial-store + reduce (no memset needed)
        float* kvp = (float*)d_ws;
        float* ksp = kvp + KVP_SZ;
        float* kvf = ksp + KSP_SZ;
        float* ksf = kvf + KVF_SZ;
        hipLaunchKernelGGL(kv_partial_kernel, dim3(NBLK_A), dim3(256), 0, stream,
                           k, v, Pm, kvp, ksp);
        hipLaunchKernelGGL(reduce_kernel, dim3(512), dim3(256), 0, stream,
                           kvp, ksp, kvf, ksf);
        hipLaunchKernelGGL(out_kernel, dim3(1024), dim3(256), 0, stream,
                           q, Pm, kvf, ksf, (float*)d_out);
    } else {
        // verified R6 fallback
        float* kvw = (float*)d_ws;
        float* ksw = kvw + (size_t)BH * MM * DD;
        hipMemsetAsync(d_ws, 0, ((size_t)BH * MM * DD + (size_t)BH * MM) * sizeof(float), stream);
        hipLaunchKernelGGL(kv_kernel, dim3(512), dim3(256), 0, stream, k, v, Pm, kvw, ksw);
        hipLaunchKernelGGL(out_kernel, dim3(1024), dim3(256), 0, stream, q, Pm, kvw, ksw, (float*)d_out);
    }
}